// Round 25
// baseline (363.676 us; speedup 1.0000x reference)
//
#include <hip/hip_runtime.h>
#include <hip/hip_bf16.h>

#define EE 128
#define HH 8
#define DDIM 16
#define NTG 8
#define CAP 64
#define PB 8
#define FFH 512
#define PHIH 64

// CONTRACT (decoded rounds 0-13): d_out is FLOAT32, out_size f32 elements.
// x_grid [0, G*3), z_grid [G*3, G*131), G = out_size/131.

struct GridParams {
  int n0, n1;
  float lo0f, hi0f, lo1f, hi1f;
  float sp0, sp1;
  float tg0, spt;
};

__device__ __forceinline__ unsigned fenc(float f) {
  unsigned u = __float_as_uint(f);
  return (u & 0x80000000u) ? ~u : (u | 0x80000000u);
}
__device__ __forceinline__ float fdec(unsigned u) {
  unsigned v = (u & 0x80000000u) ? (u ^ 0x80000000u) : ~u;
  return __uint_as_float(v);
}

__device__ __forceinline__ float gelu_f(float x) {
  const float c = 0.7978845608028654f;
  float inner = c * (x + 0.044715f * x * x * x);
  return x * (0.5f * (1.0f + tanhf(inner)));
}

__device__ __forceinline__ int cell_of(const float* __restrict__ x, const GridParams* __restrict__ gp,
                                       int p, int N_, int m, int G) {
  float x0 = x[(size_t)p * 3], x1 = x[(size_t)p * 3 + 1], x2 = x[(size_t)p * 3 + 2];
  int n0 = gp->n0, n1 = gp->n1;
  float u0 = floorf((x0 - gp->tg0) / gp->spt + 0.5f);
  u0 = fminf(fmaxf(u0, 0.0f), 7.0f);
  float u1 = floorf((x1 - gp->lo0f) / gp->sp0 + 0.5f);
  u1 = fminf(fmaxf(u1, 0.0f), (float)(n0 - 1));
  float u2 = floorf((x2 - gp->lo1f) / gp->sp1 + 0.5f);
  u2 = fminf(fmaxf(u2, 0.0f), (float)(n1 - 1));
  int it = (int)u0, i0 = (int)u1, i1 = (int)u2;
  int b = p / N_;
  int g = b * m + (it * n0 + i0) * n1 + i1;
  if (g < 0) g = 0;
  if (g >= G) g = G - 1;
  return g;
}

// ---------------- A0: init ----------------
__global__ void k_init(unsigned* mm, int* counts, int* cursor, int G) {
  int i = blockIdx.x * blockDim.x + threadIdx.x;
  if (i < G) { counts[i] = 0; cursor[i] = 0; }
  if (i == 0) { mm[0] = 0xFFFFFFFFu; mm[1] = 0xFFFFFFFFu; mm[2] = 0u; mm[3] = 0u; }
}

// ---------------- A1: global min/max ----------------
__global__ __launch_bounds__(256) void k_minmax(const float* __restrict__ x, int BN, unsigned* mm) {
  __shared__ float s0[256], s1[256], s2[256], s3[256];
  int t = threadIdx.x;
  float mn1 = 3.4e38f, mn2 = 3.4e38f, mx1 = -3.4e38f, mx2 = -3.4e38f;
  for (int p = blockIdx.x * 256 + t; p < BN; p += gridDim.x * 256) {
    float a = x[(size_t)p * 3 + 1], b = x[(size_t)p * 3 + 2];
    mn1 = fminf(mn1, a); mx1 = fmaxf(mx1, a);
    mn2 = fminf(mn2, b); mx2 = fmaxf(mx2, b);
  }
  s0[t] = mn1; s1[t] = mx1; s2[t] = mn2; s3[t] = mx2;
  __syncthreads();
  for (int off = 128; off >= 1; off >>= 1) {
    if (t < off) {
      s0[t] = fminf(s0[t], s0[t + off]); s1[t] = fmaxf(s1[t], s1[t + off]);
      s2[t] = fminf(s2[t], s2[t + off]); s3[t] = fmaxf(s3[t], s3[t + off]);
    }
    __syncthreads();
  }
  if (t == 0) {
    atomicMin(&mm[0], fenc(s0[0])); atomicMax(&mm[2], fenc(s1[0]));
    atomicMin(&mm[1], fenc(s2[0])); atomicMax(&mm[3], fenc(s3[0]));
  }
}

// ---------------- A2: bounds ----------------
__global__ __launch_bounds__(64) void k_bounds(const unsigned* mm, const float* __restrict__ tgrid,
                                               GridParams* gp) {
  if (threadIdx.x != 0 || blockIdx.x != 0) return;
  float mn1 = fdec(mm[0]), mx1 = fdec(mm[2]);
  float mn2 = fdec(mm[1]), mx2 = fdec(mm[3]);
  double lo0 = (double)mn1 - 0.1, hi0 = (double)mx1 + 0.1;
  double lo1 = (double)mn2 - 0.1, hi1 = (double)mx2 + 0.1;
  int n0 = (int)((hi0 - lo0) * 24.0);
  int n1 = (int)((hi1 - lo1) * 24.0);
  if (n0 < 2) n0 = 2;
  if (n1 < 2) n1 = 2;
  gp->n0 = n0; gp->n1 = n1;
  float lo0f = (float)lo0, hi0f = (float)hi0, lo1f = (float)lo1, hi1f = (float)hi1;
  gp->lo0f = lo0f; gp->hi0f = hi0f; gp->lo1f = lo1f; gp->hi1f = hi1f;
  gp->sp0 = (hi0f - lo0f) / (float)(n0 - 1);
  gp->sp1 = (hi1f - lo1f) / (float)(n1 - 1);
  float t0 = tgrid[0], t7 = tgrid[NTG - 1];
  gp->tg0 = t0; gp->spt = (t7 - t0) / 7.0f;
}

// ---------------- B: precompute q, v0, slot-0 logits, folded qW ----------------
__global__ __launch_bounds__(128) void k_precompute(
    const float* __restrict__ latent, const float* __restrict__ ln1g, const float* __restrict__ ln1b,
    const float* __restrict__ Wq, const float* __restrict__ Wk, const float* __restrict__ Wv,
    const float* __restrict__ pb1, const float* __restrict__ pw2, const float* __restrict__ pb2,
    float* qvec, float* v0g, float* dot0g, float* qWg) {
  __shared__ float sbuf[EE], zqn[EE], qls[EE], k0[EE], h64[PHIH], stat[2];
  int t = threadIdx.x;
  float lat = latent[t];
  sbuf[t] = lat; __syncthreads();
  for (int off = 64; off >= 1; off >>= 1) { if (t < off) sbuf[t] += sbuf[t + off]; __syncthreads(); }
  if (t == 0) stat[0] = sbuf[0] * (1.0f / 128.0f);
  __syncthreads();
  float dv = lat - stat[0];
  sbuf[t] = dv * dv; __syncthreads();
  for (int off = 64; off >= 1; off >>= 1) { if (t < off) sbuf[t] += sbuf[t + off]; __syncthreads(); }
  if (t == 0) stat[1] = sqrtf(sbuf[0] * (1.0f / 128.0f) + 1e-5f);
  __syncthreads();
  zqn[t] = (lat - stat[0]) / stat[1] * ln1g[t] + ln1b[t];
  __syncthreads();
  float q = 0, k = 0, v = 0;
  for (int e = 0; e < EE; ++e) {
    float zn = zqn[e];
    q += zn * Wq[e * EE + t];
    k += zn * Wk[e * EE + t];
    v += zn * Wv[e * EE + t];
  }
  qvec[t] = q; v0g[t] = v; qls[t] = q; k0[t] = k;
  __syncthreads();
  // Folded query: qW[h][e] = 0.25 * sum_d q[h*16+d] * Wk[e][h*16+d]
  for (int h = 0; h < HH; ++h) {
    float s = 0;
    #pragma unroll
    for (int d = 0; d < DDIM; ++d) s += qls[h * DDIM + d] * Wk[t * EE + h * DDIM + d];
    qWg[h * EE + t] = 0.25f * s;
  }
  if (t < PHIH) h64[t] = gelu_f(pb1[t]);
  __syncthreads();
  if (t < HH) {
    float s = 0;
    for (int d = 0; d < DDIM; ++d) s += qls[t * DDIM + d] * k0[t * DDIM + d];
    s *= 0.25f;
    float te = pb2[t];
    for (int u = 0; u < PHIH; ++u) te += h64[u] * pw2[u * HH + t];
    dot0g[t] = s + te;
  }
}

// ---------------- A3: count ----------------
__global__ __launch_bounds__(256) void k_assign(
    const float* __restrict__ x, const GridParams* __restrict__ gp,
    int* __restrict__ counts, int BN, int N_, int m, int G) {
  int p = blockIdx.x * 256 + threadIdx.x;
  if (p >= BN) return;
  int g = cell_of(x, gp, p, N_, m, G);
  atomicAdd(&counts[g], 1);
}

// ---------------- A4: prefix scan ----------------
__global__ __launch_bounds__(1024) void k_scan(const int* __restrict__ counts,
                                               int* __restrict__ offsets, int G) {
  __shared__ int part[1024];
  int t = threadIdx.x;
  int chunk = (G + 1023) / 1024;
  int lo = t * chunk, hi = lo + chunk; if (hi > G) hi = G; if (lo > G) lo = G;
  int s = 0;
  for (int i = lo; i < hi; ++i) s += counts[i];
  part[t] = s;
  __syncthreads();
  for (int off = 1; off < 1024; off <<= 1) {
    int v = (t >= off) ? part[t - off] : 0;
    __syncthreads();
    part[t] += v;
    __syncthreads();
  }
  int run = (t == 0) ? 0 : part[t - 1];
  for (int i = lo; i < hi; ++i) { offsets[i] = run; run += counts[i]; }
}

// ---------------- A5: scatter ----------------
__global__ __launch_bounds__(256) void k_scatter(
    const float* __restrict__ x, const GridParams* __restrict__ gp,
    const int* __restrict__ offsets, int* __restrict__ cursor,
    int* __restrict__ compact, int BN, int N_, int m, int G) {
  int p = blockIdx.x * 256 + threadIdx.x;
  if (p >= BN) return;
  int g = cell_of(x, gp, p, N_, m, G);
  int r = atomicAdd(&cursor[g], 1);
  int idx = offsets[g] + r;
  if (idx >= 0 && idx < BN) compact[idx] = p;
}

// ---------------- C: per-cell cross-attention (WAVE-PER-CELL, zero barriers) ----------------
// One 64-lane wave owns one cell. Block = 2 waves = 2 independent cells.
// No __syncthreads anywhere: all LDS dependencies are intra-wave (lockstep).
__global__ __launch_bounds__(128) void k_cell(
    const float* __restrict__ x, const float* __restrict__ z,
    const float* __restrict__ tgrid, const float* __restrict__ latent,
    const float* __restrict__ ln1g, const float* __restrict__ ln1b,
    const float* __restrict__ Wv, const float* __restrict__ Wo, const float* __restrict__ bo,
    const float* __restrict__ pw1, const float* __restrict__ pb1,
    const float* __restrict__ pw2, const float* __restrict__ pb2,
    const float* __restrict__ qWg, const float* __restrict__ v0g, const float* __restrict__ dot0g,
    const GridParams* __restrict__ gp,
    const int* __restrict__ counts, const int* __restrict__ offsets,
    const int* __restrict__ compact,
    float* __restrict__ outx, float* __restrict__ outz, int m, int BN, int G) {
  __shared__ __align__(16) float zbS[2][PB * 132];   // z rows; epilogue: zbl[8][128]
  __shared__ __align__(16) float hbS[2][PB][68];     // TE hidden
  __shared__ __align__(16) float pw2TS[2][HH][68];   // pw2 transposed (per wave)
  __shared__ __align__(16) float wsmS[2][PB][8];     // softmax weights (this batch)
  __shared__ __align__(16) float oslS[2][EE];
  __shared__ float dotbS[2][CAP][9];
  __shared__ float diffbS[2][CAP][3];
  __shared__ float mlS[2][PB], ivS[2][PB];
  __shared__ float mhS[2][HH], lhS[2][HH], schS[2][HH];
  __shared__ float asumS[2][CAP];

  int t = threadIdx.x;
  int w = t >> 6, l = t & 63;
  int cell = blockIdx.x * 2 + w;
  if (cell >= G) return;

  int b = cell / m, c = cell % m;
  int n0 = gp->n0, n1 = gp->n1;
  int nn = n0 * n1;
  int it = (nn > 0) ? (c / nn) : 0;
  int r2 = (nn > 0) ? (c % nn) : 0;
  int i0 = (n1 > 0) ? (r2 / n1) : 0;
  int i1 = (n1 > 0) ? (r2 % n1) : 0;
  int cnt = counts[cell]; if (cnt > CAP) cnt = CAP; if (cnt < 0) cnt = 0;
  int start = offsets[cell];
  if (start < 0) start = 0;
  if (start > BN - cnt) start = BN - cnt;

  // xqs computed redundantly in every lane (registers, no LDS dep)
  float xq0, xq1, xq2;
  {
    int tidx = b * NTG + it;
    if (tidx < 0) tidx = 0;
    if (tidx > 2 * NTG - 1) tidx = 2 * NTG - 1;
    xq0 = tgrid[tidx];
    if (i0 == n0 - 1) xq1 = gp->hi0f;
    else xq1 = __fadd_rn(gp->lo0f, __fmul_rn((float)i0, gp->sp0));
    if (i1 == n1 - 1) xq2 = gp->hi1f;
    else xq2 = __fadd_rn(gp->lo1f, __fmul_rn((float)i1, gp->sp1));
  }
  if (l < HH) { mhS[w][l] = dot0g[l]; lhS[w][l] = 1.0f; }
  // stage pw2T per wave
  for (int w2 = l; w2 < HH * PHIH; w2 += 64) pw2TS[w][w2 & 7][w2 >> 3] = pw2[w2];
  // diffb: lane j = l handles row l
  if (l < cnt) {
    int pid = compact[start + l];
    bool ok = (pid >= 0 && pid < BN);
    diffbS[w][l][0] = ok ? (xq0 - x[(size_t)pid * 3 + 0]) : 0.0f;
    diffbS[w][l][1] = ok ? (xq1 - x[(size_t)pid * 3 + 1]) : 0.0f;
    diffbS[w][l][2] = ok ? (xq2 - x[(size_t)pid * 3 + 2]) : 0.0f;
  }

  float g1a = ln1g[l], b1a = ln1b[l];
  float g1b = ln1g[l + 64], b1b = ln1b[l + 64];
  float zbarA[8], zbarB[8];
  #pragma unroll
  for (int h = 0; h < 8; ++h) { zbarA[h] = 0.0f; zbarB[h] = 0.0f; }
  float* zb = zbS[w];

  for (int jb = 0; jb < cnt; jb += PB) {
    int nb = min(PB, cnt - jb);
    // 1. z -> LDS: lane l loads features l and l+64 of each row (parallel issue)
    #pragma unroll
    for (int pp = 0; pp < PB; ++pp) {
      if (pp < nb) {
        int pid = compact[start + jb + pp];
        float a = 0.0f, c2 = 0.0f;
        if (pid >= 0 && pid < BN) {
          a  = z[(size_t)pid * EE + l];
          c2 = z[(size_t)pid * EE + l + 64];
        }
        zb[pp * 132 + l] = a;
        zb[pp * 132 + l + 64] = c2;
      }
    }
    // 2. LN stats: (pp = l>>3, sub = l&7)
    {
      int pp = l >> 3, sub = l & 7;
      float s = 0;
      #pragma unroll
      for (int k2 = 0; k2 < 16; ++k2) s += zb[pp * 132 + sub + 8 * k2];
      s += __shfl_xor(s, 1); s += __shfl_xor(s, 2); s += __shfl_xor(s, 4);
      float mean = s * (1.0f / 128.0f);
      float v = 0;
      #pragma unroll
      for (int k2 = 0; k2 < 16; ++k2) { float d = zb[pp * 132 + sub + 8 * k2] - mean; v += d * d; }
      v += __shfl_xor(v, 1); v += __shfl_xor(v, 2); v += __shfl_xor(v, 4);
      if (sub == 0) { mlS[w][pp] = mean; ivS[w][pp] = 1.0f / sqrtf(v * (1.0f / 128.0f) + 1e-5f); }
    }
    // 3. normalize (both feature halves, valid rows) + TE hidden
    #pragma unroll
    for (int pp = 0; pp < PB; ++pp) {
      if (pp < nb) {
        float mean = mlS[w][pp], inv = ivS[w][pp];
        zb[pp * 132 + l]      = (zb[pp * 132 + l]      - mean) * inv * g1a + b1a;
        zb[pp * 132 + l + 64] = (zb[pp * 132 + l + 64] - mean) * inv * g1b + b1b;
      }
    }
    for (int w2 = l; w2 < PB * PHIH; w2 += 64) {
      int pp = w2 >> 6, u = w2 & 63;
      int j = jb + pp;
      float d0 = 0, d1 = 0, d2 = 0;
      if (j < cnt) { d0 = diffbS[w][j][0]; d1 = diffbS[w][j][1]; d2 = diffbS[w][j][2]; }
      float hv = pb1[u] + d0 * pw1[u] + d1 * pw1[PHIH + u] + d2 * pw1[2 * PHIH + u];
      hbS[w][pp][u] = gelu_f(hv);
    }
    // 4. logits: (pp = l>>3, h = l&7) — exactly 64 lanes
    {
      int pp = l >> 3, h = l & 7;
      float dacc = 0;
      #pragma unroll
      for (int e4 = 0; e4 < 32; ++e4) {
        float4 zn4 = *(const float4*)&zb[pp * 132 + e4 * 4];
        float4 qw4 = *(const float4*)&qWg[h * EE + e4 * 4];
        dacc += zn4.x * qw4.x + zn4.y * qw4.y + zn4.z * qw4.z + zn4.w * qw4.w;
      }
      float te = pb2[h];
      #pragma unroll
      for (int u4 = 0; u4 < 16; ++u4) {
        float4 hb = *(const float4*)&hbS[w][pp][u4 * 4];
        float4 p2 = *(const float4*)&pw2TS[w][h][u4 * 4];
        te += hb.x * p2.x + hb.y * p2.y + hb.z * p2.z + hb.w * p2.w;
      }
      if (pp < nb) dotbS[w][jb + pp][h] = dacc + te;
    }
    // 5+6 fused: online softmax + batch weights (lanes l<8 = head)
    if (l < HH) {
      float mold = mhS[w][l], mb = mold;
      for (int pp = 0; pp < nb; ++pp) mb = fmaxf(mb, dotbS[w][jb + pp][l]);
      float sc = expf(mold - mb);
      float ls = lhS[w][l] * sc;
      for (int pp = 0; pp < nb; ++pp) {
        float wv = expf(dotbS[w][jb + pp][l] - mb);
        wsmS[w][pp][l] = wv;
        ls += wv;
      }
      mhS[w][l] = mb; lhS[w][l] = ls; schS[w][l] = sc;
    }
    // 7. zbar update (lane = features l, l+64)
    {
      #pragma unroll
      for (int h = 0; h < 8; ++h) { float sc = schS[w][h]; zbarA[h] *= sc; zbarB[h] *= sc; }
      for (int pp = 0; pp < nb; ++pp) {
        float znA = zb[pp * 132 + l], znB = zb[pp * 132 + l + 64];
        float4 wa = *(const float4*)&wsmS[w][pp][0];
        float4 wb = *(const float4*)&wsmS[w][pp][4];
        zbarA[0] += wa.x * znA; zbarA[1] += wa.y * znA; zbarA[2] += wa.z * znA; zbarA[3] += wa.w * znA;
        zbarA[4] += wb.x * znA; zbarA[5] += wb.y * znA; zbarA[6] += wb.z * znA; zbarA[7] += wb.w * znA;
        zbarB[0] += wa.x * znB; zbarB[1] += wa.y * znB; zbarB[2] += wa.z * znB; zbarB[3] += wa.w * znB;
        zbarB[4] += wb.x * znB; zbarB[5] += wb.y * znB; zbarB[6] += wb.z * znB; zbarB[7] += wb.w * znB;
      }
    }
  }

  // epilogue: stage zbl into zb area ([h][e] flat, 8*128 <= 8*132)
  #pragma unroll
  for (int h = 0; h < 8; ++h) {
    zb[h * EE + l] = zbarA[h];
    zb[h * EE + l + 64] = zbarB[h];
  }
  if (l < cnt) {
    float s = 0;
    #pragma unroll
    for (int h2 = 0; h2 < HH; ++h2)
      s += expf(dotbS[w][l][h2] - mhS[w][h2]) / lhS[w][h2];
    asumS[w][l] = s;
  }
  // osh for features l and l+64
  {
    int e0 = l, e1 = l + 64;
    int h0 = e0 >> 4, h1 = e1 >> 4;
    float os0 = 0, os1 = 0;
    for (int ep = 0; ep < EE; ++ep) {
      os0 += zb[h0 * EE + ep] * Wv[ep * EE + e0];
      os1 += zb[h1 * EE + ep] * Wv[ep * EE + e1];
    }
    float w00 = expf(dot0g[h0] - mhS[w][h0]) / lhS[w][h0];
    float w01 = expf(dot0g[h1] - mhS[w][h1]) / lhS[w][h1];
    oslS[w][e0] = w00 * v0g[e0] + os0 / lhS[w][h0];
    oslS[w][e1] = w01 * v0g[e1] + os1 / lhS[w][h1];
  }
  // Wo matvec + residual for both features
  {
    float acc0 = 0, acc1 = 0;
    for (int ep = 0; ep < EE; ++ep) {
      float ov = oslS[w][ep];
      acc0 += ov * Wo[ep * EE + l];
      acc1 += ov * Wo[ep * EE + l + 64];
    }
    outz[(size_t)cell * EE + l] = latent[l] + acc0 + bo[l];
    outz[(size_t)cell * EE + l + 64] = latent[l + 64] + acc1 + bo[l + 64];
  }
  if (l < 3) {
    float a = 0;
    for (int j = 0; j < cnt; ++j) a += asumS[w][j] * diffbS[w][j][l];
    float xc = (l == 0) ? xq0 : ((l == 1) ? xq1 : xq2);
    outx[(size_t)cell * 3 + l] = xc - a * (1.0f / 8.0f);
  }
}

// ---------------- D: FFN (8 rows per block, 512 threads, f32 in-place) ----------------
__global__ __launch_bounds__(512) void k_ffn(
    const float* __restrict__ ln2g, const float* __restrict__ ln2b,
    const float* __restrict__ fw1, const float* __restrict__ fb1,
    const float* __restrict__ fw2, const float* __restrict__ fb2,
    float* __restrict__ outz, int G) {
  __shared__ float zn[8][EE];
  __shared__ float zr[8][EE];
  __shared__ float gh[8][FFH];
  __shared__ float mv[8], sv[8];
  int t = threadIdx.x;
  int base = blockIdx.x * 8;
  for (int w = t; w < 8 * EE; w += 512) {
    int r = w >> 7, e = w & 127;
    int cell = base + r;
    float v = (cell < G) ? outz[(size_t)cell * EE + e] : 0.0f;
    zn[r][e] = v; zr[r][e] = v;
  }
  __syncthreads();
  {
    int r = t >> 6, lane = t & 63;
    float s = zn[r][lane] + zn[r][lane + 64];
    s += __shfl_xor(s, 1); s += __shfl_xor(s, 2); s += __shfl_xor(s, 4);
    s += __shfl_xor(s, 8); s += __shfl_xor(s, 16); s += __shfl_xor(s, 32);
    float mean = s * (1.0f / 128.0f);
    float d0 = zn[r][lane] - mean, d1 = zn[r][lane + 64] - mean;
    float v = d0 * d0 + d1 * d1;
    v += __shfl_xor(v, 1); v += __shfl_xor(v, 2); v += __shfl_xor(v, 4);
    v += __shfl_xor(v, 8); v += __shfl_xor(v, 16); v += __shfl_xor(v, 32);
    if (lane == 0) { mv[r] = mean; sv[r] = sqrtf(v * (1.0f / 128.0f) + 1e-5f); }
  }
  __syncthreads();
  for (int w = t; w < 8 * EE; w += 512) {
    int r = w >> 7, e = w & 127;
    zn[r][e] = (zn[r][e] - mv[r]) / sv[r] * ln2g[e] + ln2b[e];
  }
  __syncthreads();
  {
    int j = t;
    float acc[8];
    #pragma unroll
    for (int r = 0; r < 8; ++r) acc[r] = 0;
    for (int e = 0; e < EE; ++e) {
      float w = fw1[e * FFH + j];
      #pragma unroll
      for (int r = 0; r < 8; ++r) acc[r] += zn[r][e] * w;
    }
    float fb = fb1[j];
    #pragma unroll
    for (int r = 0; r < 8; ++r) gh[r][j] = gelu_f(acc[r] + fb);
  }
  __syncthreads();
  {
    int e = t & 127; int rb = (t >> 7) * 2;
    float a2[2];
    a2[0] = 0; a2[1] = 0;
    for (int j = 0; j < FFH; ++j) {
      float w = fw2[j * EE + e];
      a2[0] += gh[rb + 0][j] * w;
      a2[1] += gh[rb + 1][j] * w;
    }
    #pragma unroll
    for (int rr = 0; rr < 2; ++rr) {
      int cell = base + rb + rr;
      if (cell < G) outz[(size_t)cell * EE + e] = zr[rb + rr][e] + (a2[rr] + fb2[e]);
    }
  }
}

extern "C" void kernel_launch(void* const* d_in, const int* in_sizes, int n_in,
                              void* d_out, int out_size, void* d_ws, size_t ws_size,
                              hipStream_t stream) {
  const float* x     = (const float*)d_in[0];
  const float* z     = (const float*)d_in[1];
  const float* tgrid = (const float*)d_in[2];
  const float* latent= (const float*)d_in[3];
  const float* ln1g  = (const float*)d_in[4];
  const float* ln1b  = (const float*)d_in[5];
  const float* ln2g  = (const float*)d_in[6];
  const float* ln2b  = (const float*)d_in[7];
  const float* Wq    = (const float*)d_in[8];
  const float* Wk    = (const float*)d_in[9];
  const float* Wv    = (const float*)d_in[10];
  const float* Wo    = (const float*)d_in[11];
  const float* bo    = (const float*)d_in[12];
  const float* pw1   = (const float*)d_in[13];
  const float* pb1   = (const float*)d_in[14];
  const float* pw2   = (const float*)d_in[15];
  const float* pb2   = (const float*)d_in[16];
  const float* fw1   = (const float*)d_in[17];
  const float* fb1   = (const float*)d_in[18];
  const float* fw2   = (const float*)d_in[19];
  const float* fb2   = (const float*)d_in[20];
  (void)n_in; (void)ws_size;

  int Bn = in_sizes[2] / NTG;
  int BN = in_sizes[0] / 3;
  int N_ = BN / Bn;
  int G  = out_size / 131;
  int m  = G / Bn;

  char* ws = (char*)d_ws;
  unsigned* mm    = (unsigned*)ws;
  GridParams* gp  = (GridParams*)(ws + 64);
  float* qvec     = (float*)(ws + 128);
  float* v0g      = (float*)(ws + 128 + 512);
  float* dot0g    = (float*)(ws + 128 + 1024);
  float* qWg      = (float*)(ws + 2048);          // 8*128 f32 = 4096 B
  size_t off = 8192;
  int* counts     = (int*)(ws + off); off += (size_t)G * 4;
  int* offsets    = (int*)(ws + off); off += (size_t)G * 4;
  int* cursor     = (int*)(ws + off); off += (size_t)G * 4;
  int* compact    = (int*)(ws + off); off += (size_t)BN * 4;

  float* outx = (float*)d_out;
  float* outz = outx + (size_t)G * 3;

  hipLaunchKernelGGL(k_init, dim3((G + 255) / 256), dim3(256), 0, stream, mm, counts, cursor, G);
  hipLaunchKernelGGL(k_minmax, dim3(256), dim3(256), 0, stream, x, BN, mm);
  hipLaunchKernelGGL(k_bounds, dim3(1), dim3(64), 0, stream, mm, tgrid, gp);
  hipLaunchKernelGGL(k_precompute, dim3(1), dim3(128), 0, stream,
                     latent, ln1g, ln1b, Wq, Wk, Wv, pb1, pw2, pb2, qvec, v0g, dot0g, qWg);
  hipLaunchKernelGGL(k_assign, dim3((BN + 255) / 256), dim3(256), 0, stream,
                     x, gp, counts, BN, N_, m, G);
  hipLaunchKernelGGL(k_scan, dim3(1), dim3(1024), 0, stream, counts, offsets, G);
  hipLaunchKernelGGL(k_scatter, dim3((BN + 255) / 256), dim3(256), 0, stream,
                     x, gp, offsets, cursor, compact, BN, N_, m, G);
  hipLaunchKernelGGL(k_cell, dim3((G + 1) / 2), dim3(128), 0, stream,
                     x, z, tgrid, latent, ln1g, ln1b, Wv, Wo, bo,
                     pw1, pb1, pw2, pb2, qWg, v0g, dot0g, gp, counts, offsets, compact,
                     outx, outz, m, BN, G);
  hipLaunchKernelGGL(k_ffn, dim3((G + 7) / 8), dim3(512), 0, stream,
                     ln2g, ln2b, fw1, fb1, fw2, fb2, outz, G);
}

// Round 26
// 334.769 us; speedup vs baseline: 1.0863x; 1.0863x over previous
//
#include <hip/hip_runtime.h>
#include <hip/hip_bf16.h>

#define EE 128
#define HH 8
#define DDIM 16
#define NTG 8
#define CAP 64
#define PB 16
#define FFH 512
#define PHIH 64

// CONTRACT (decoded rounds 0-13): d_out is FLOAT32, out_size f32 elements.
// x_grid [0, G*3), z_grid [G*3, G*131), G = out_size/131.

struct GridParams {
  int n0, n1;
  float lo0f, hi0f, lo1f, hi1f;
  float sp0, sp1;
  float tg0, spt;
};

__device__ __forceinline__ unsigned fenc(float f) {
  unsigned u = __float_as_uint(f);
  return (u & 0x80000000u) ? ~u : (u | 0x80000000u);
}
__device__ __forceinline__ float fdec(unsigned u) {
  unsigned v = (u & 0x80000000u) ? (u ^ 0x80000000u) : ~u;
  return __uint_as_float(v);
}

__device__ __forceinline__ float gelu_f(float x) {
  const float c = 0.7978845608028654f;
  float inner = c * (x + 0.044715f * x * x * x);
  return x * (0.5f * (1.0f + tanhf(inner)));
}

__device__ __forceinline__ int cell_of(const float* __restrict__ x, const GridParams* __restrict__ gp,
                                       int p, int N_, int m, int G) {
  float x0 = x[(size_t)p * 3], x1 = x[(size_t)p * 3 + 1], x2 = x[(size_t)p * 3 + 2];
  int n0 = gp->n0, n1 = gp->n1;
  float u0 = floorf((x0 - gp->tg0) / gp->spt + 0.5f);
  u0 = fminf(fmaxf(u0, 0.0f), 7.0f);
  float u1 = floorf((x1 - gp->lo0f) / gp->sp0 + 0.5f);
  u1 = fminf(fmaxf(u1, 0.0f), (float)(n0 - 1));
  float u2 = floorf((x2 - gp->lo1f) / gp->sp1 + 0.5f);
  u2 = fminf(fmaxf(u2, 0.0f), (float)(n1 - 1));
  int it = (int)u0, i0 = (int)u1, i1 = (int)u2;
  int b = p / N_;
  int g = b * m + (it * n0 + i0) * n1 + i1;
  if (g < 0) g = 0;
  if (g >= G) g = G - 1;
  return g;
}

// ---------------- A0: init ----------------
__global__ void k_init(unsigned* mm, int* counts, int* cursor, int G) {
  int i = blockIdx.x * blockDim.x + threadIdx.x;
  if (i < G) { counts[i] = 0; cursor[i] = 0; }
  if (i == 0) { mm[0] = 0xFFFFFFFFu; mm[1] = 0xFFFFFFFFu; mm[2] = 0u; mm[3] = 0u; }
}

// ---------------- A1: global min/max ----------------
__global__ __launch_bounds__(256) void k_minmax(const float* __restrict__ x, int BN, unsigned* mm) {
  __shared__ float s0[256], s1[256], s2[256], s3[256];
  int t = threadIdx.x;
  float mn1 = 3.4e38f, mn2 = 3.4e38f, mx1 = -3.4e38f, mx2 = -3.4e38f;
  for (int p = blockIdx.x * 256 + t; p < BN; p += gridDim.x * 256) {
    float a = x[(size_t)p * 3 + 1], b = x[(size_t)p * 3 + 2];
    mn1 = fminf(mn1, a); mx1 = fmaxf(mx1, a);
    mn2 = fminf(mn2, b); mx2 = fmaxf(mx2, b);
  }
  s0[t] = mn1; s1[t] = mx1; s2[t] = mn2; s3[t] = mx2;
  __syncthreads();
  for (int off = 128; off >= 1; off >>= 1) {
    if (t < off) {
      s0[t] = fminf(s0[t], s0[t + off]); s1[t] = fmaxf(s1[t], s1[t + off]);
      s2[t] = fminf(s2[t], s2[t + off]); s3[t] = fmaxf(s3[t], s3[t + off]);
    }
    __syncthreads();
  }
  if (t == 0) {
    atomicMin(&mm[0], fenc(s0[0])); atomicMax(&mm[2], fenc(s1[0]));
    atomicMin(&mm[1], fenc(s2[0])); atomicMax(&mm[3], fenc(s3[0]));
  }
}

// ---------------- A2: bounds ----------------
__global__ __launch_bounds__(64) void k_bounds(const unsigned* mm, const float* __restrict__ tgrid,
                                               GridParams* gp) {
  if (threadIdx.x != 0 || blockIdx.x != 0) return;
  float mn1 = fdec(mm[0]), mx1 = fdec(mm[2]);
  float mn2 = fdec(mm[1]), mx2 = fdec(mm[3]);
  double lo0 = (double)mn1 - 0.1, hi0 = (double)mx1 + 0.1;
  double lo1 = (double)mn2 - 0.1, hi1 = (double)mx2 + 0.1;
  int n0 = (int)((hi0 - lo0) * 24.0);
  int n1 = (int)((hi1 - lo1) * 24.0);
  if (n0 < 2) n0 = 2;
  if (n1 < 2) n1 = 2;
  gp->n0 = n0; gp->n1 = n1;
  float lo0f = (float)lo0, hi0f = (float)hi0, lo1f = (float)lo1, hi1f = (float)hi1;
  gp->lo0f = lo0f; gp->hi0f = hi0f; gp->lo1f = lo1f; gp->hi1f = hi1f;
  gp->sp0 = (hi0f - lo0f) / (float)(n0 - 1);
  gp->sp1 = (hi1f - lo1f) / (float)(n1 - 1);
  float t0 = tgrid[0], t7 = tgrid[NTG - 1];
  gp->tg0 = t0; gp->spt = (t7 - t0) / 7.0f;
}

// ---------------- B: precompute q, v0, slot-0 logits, folded qW ----------------
__global__ __launch_bounds__(128) void k_precompute(
    const float* __restrict__ latent, const float* __restrict__ ln1g, const float* __restrict__ ln1b,
    const float* __restrict__ Wq, const float* __restrict__ Wk, const float* __restrict__ Wv,
    const float* __restrict__ pb1, const float* __restrict__ pw2, const float* __restrict__ pb2,
    float* qvec, float* v0g, float* dot0g, float* qWg) {
  __shared__ float sbuf[EE], zqn[EE], qls[EE], k0[EE], h64[PHIH], stat[2];
  int t = threadIdx.x;
  float lat = latent[t];
  sbuf[t] = lat; __syncthreads();
  for (int off = 64; off >= 1; off >>= 1) { if (t < off) sbuf[t] += sbuf[t + off]; __syncthreads(); }
  if (t == 0) stat[0] = sbuf[0] * (1.0f / 128.0f);
  __syncthreads();
  float dv = lat - stat[0];
  sbuf[t] = dv * dv; __syncthreads();
  for (int off = 64; off >= 1; off >>= 1) { if (t < off) sbuf[t] += sbuf[t + off]; __syncthreads(); }
  if (t == 0) stat[1] = sqrtf(sbuf[0] * (1.0f / 128.0f) + 1e-5f);
  __syncthreads();
  zqn[t] = (lat - stat[0]) / stat[1] * ln1g[t] + ln1b[t];
  __syncthreads();
  float q = 0, k = 0, v = 0;
  for (int e = 0; e < EE; ++e) {
    float zn = zqn[e];
    q += zn * Wq[e * EE + t];
    k += zn * Wk[e * EE + t];
    v += zn * Wv[e * EE + t];
  }
  qvec[t] = q; v0g[t] = v; qls[t] = q; k0[t] = k;
  __syncthreads();
  // Folded query: qW[h][e] = 0.25 * sum_d q[h*16+d] * Wk[e][h*16+d]
  for (int h = 0; h < HH; ++h) {
    float s = 0;
    #pragma unroll
    for (int d = 0; d < DDIM; ++d) s += qls[h * DDIM + d] * Wk[t * EE + h * DDIM + d];
    qWg[h * EE + t] = 0.25f * s;
  }
  if (t < PHIH) h64[t] = gelu_f(pb1[t]);
  __syncthreads();
  if (t < HH) {
    float s = 0;
    for (int d = 0; d < DDIM; ++d) s += qls[t * DDIM + d] * k0[t * DDIM + d];
    s *= 0.25f;
    float te = pb2[t];
    for (int u = 0; u < PHIH; ++u) te += h64[u] * pw2[u * HH + t];
    dot0g[t] = s + te;
  }
}

// ---------------- A3: count ----------------
__global__ __launch_bounds__(256) void k_assign(
    const float* __restrict__ x, const GridParams* __restrict__ gp,
    int* __restrict__ counts, int BN, int N_, int m, int G) {
  int p = blockIdx.x * 256 + threadIdx.x;
  if (p >= BN) return;
  int g = cell_of(x, gp, p, N_, m, G);
  atomicAdd(&counts[g], 1);
}

// ---------------- A4: prefix scan ----------------
__global__ __launch_bounds__(1024) void k_scan(const int* __restrict__ counts,
                                               int* __restrict__ offsets, int G) {
  __shared__ int part[1024];
  int t = threadIdx.x;
  int chunk = (G + 1023) / 1024;
  int lo = t * chunk, hi = lo + chunk; if (hi > G) hi = G; if (lo > G) lo = G;
  int s = 0;
  for (int i = lo; i < hi; ++i) s += counts[i];
  part[t] = s;
  __syncthreads();
  for (int off = 1; off < 1024; off <<= 1) {
    int v = (t >= off) ? part[t - off] : 0;
    __syncthreads();
    part[t] += v;
    __syncthreads();
  }
  int run = (t == 0) ? 0 : part[t - 1];
  for (int i = lo; i < hi; ++i) { offsets[i] = run; run += counts[i]; }
}

// ---------------- A5: scatter ----------------
__global__ __launch_bounds__(256) void k_scatter(
    const float* __restrict__ x, const GridParams* __restrict__ gp,
    const int* __restrict__ offsets, int* __restrict__ cursor,
    int* __restrict__ compact, int BN, int N_, int m, int G) {
  int p = blockIdx.x * 256 + threadIdx.x;
  if (p >= BN) return;
  int g = cell_of(x, gp, p, N_, m, G);
  int r = atomicAdd(&cursor[g], 1);
  int idx = offsets[g] + r;
  if (idx >= 0 && idx < BN) compact[idx] = p;
}

// ---------------- C: per-cell cross-attention (r24 + __expf fast exp) ----------------
__global__ __launch_bounds__(128) void k_cell(
    const float* __restrict__ x, const float* __restrict__ z,
    const float* __restrict__ tgrid, const float* __restrict__ latent,
    const float* __restrict__ ln1g, const float* __restrict__ ln1b,
    const float* __restrict__ Wv, const float* __restrict__ Wo, const float* __restrict__ bo,
    const float* __restrict__ pw1, const float* __restrict__ pb1,
    const float* __restrict__ pw2, const float* __restrict__ pb2,
    const float* __restrict__ qWg, const float* __restrict__ v0g, const float* __restrict__ dot0g,
    const GridParams* __restrict__ gp,
    const int* __restrict__ counts, const int* __restrict__ offsets,
    const int* __restrict__ compact,
    float* __restrict__ outx, float* __restrict__ outz, int m, int BN) {
  __shared__ __align__(16) float zb[PB][132];     // raw -> normalized z
  __shared__ __align__(16) float hbuf[PB][68];    // TE hidden; epilogue: aliased as zbl[8][128]
  __shared__ __align__(16) float pw2T[HH][68];    // pw2 transposed
  __shared__ __align__(16) float wsm[PB][8];      // softmax weights (this batch)
  __shared__ float dotb[CAP][9];                  // raw logits (kept for asum)
  __shared__ float diffb[CAP][3];
  __shared__ float meanl[PB], invl[PB];
  __shared__ float mh[HH], lh[HH], sch[HH];
  __shared__ __align__(16) float osh[EE];
  __shared__ float asum[CAP];
  __shared__ float xqs[3];

  int t = threadIdx.x;
  int cell = blockIdx.x;
  int b = cell / m, c = cell % m;
  int n0 = gp->n0, n1 = gp->n1;
  int nn = n0 * n1;
  int it = (nn > 0) ? (c / nn) : 0;
  int r2 = (nn > 0) ? (c % nn) : 0;
  int i0 = (n1 > 0) ? (r2 / n1) : 0;
  int i1 = (n1 > 0) ? (r2 % n1) : 0;
  int cnt = counts[cell]; if (cnt > CAP) cnt = CAP; if (cnt < 0) cnt = 0;
  int start = offsets[cell];
  if (start < 0) start = 0;
  if (start > BN - cnt) start = BN - cnt;

  float g1 = ln1g[t], b1 = ln1b[t];
  float zbar[8];
  #pragma unroll
  for (int h = 0; h < 8; ++h) zbar[h] = 0.0f;
  if (t < HH) { mh[t] = dot0g[t]; lh[t] = 1.0f; }
  if (t == 0) {
    int tidx = b * NTG + it;
    if (tidx < 0) tidx = 0;
    if (tidx > 2 * NTG - 1) tidx = 2 * NTG - 1;
    xqs[0] = tgrid[tidx];
    float v;
    if (i0 == n0 - 1) v = gp->hi0f;
    else v = __fadd_rn(gp->lo0f, __fmul_rn((float)i0, gp->sp0));
    xqs[1] = v;
    if (i1 == n1 - 1) v = gp->hi1f;
    else v = __fadd_rn(gp->lo1f, __fmul_rn((float)i1, gp->sp1));
    xqs[2] = v;
  }
  for (int w = t; w < PHIH * HH; w += 128) pw2T[w & 7][w >> 3] = pw2[w];
  __syncthreads();
  for (int w = t; w < cnt * 3; w += 128) {
    int j = w / 3, d = w % 3;
    int pid = compact[start + j];
    diffb[j][d] = (pid >= 0 && pid < BN) ? (xqs[d] - x[(size_t)pid * 3 + d]) : 0.0f;
  }
  __syncthreads();

  for (int jb = 0; jb < cnt; jb += PB) {
    int nb = min(PB, cnt - jb);
    // 1. raw z -> LDS (static unroll + predication)
    #pragma unroll
    for (int pp = 0; pp < PB; ++pp) {
      float zval = 0.0f;
      if (pp < nb) {
        int pid = compact[start + jb + pp];
        if (pid >= 0 && pid < BN) zval = z[(size_t)pid * EE + t];
      }
      zb[pp][t] = zval;
    }
    __syncthreads();
    // 2. LN stats: (pp = t>>3, sub = t&7)
    {
      int pp = t >> 3, sub = t & 7;
      float s = 0;
      #pragma unroll
      for (int k2 = 0; k2 < 16; ++k2) s += zb[pp][sub + 8 * k2];
      s += __shfl_xor(s, 1); s += __shfl_xor(s, 2); s += __shfl_xor(s, 4);
      float mean = s * (1.0f / 128.0f);
      float v = 0;
      #pragma unroll
      for (int k2 = 0; k2 < 16; ++k2) { float d = zb[pp][sub + 8 * k2] - mean; v += d * d; }
      v += __shfl_xor(v, 1); v += __shfl_xor(v, 2); v += __shfl_xor(v, 4);
      if (sub == 0) { meanl[pp] = mean; invl[pp] = 1.0f / sqrtf(v * (1.0f / 128.0f) + 1e-5f); }
    }
    __syncthreads();
    // 3. normalize in place + TE hidden
    #pragma unroll
    for (int pp = 0; pp < PB; ++pp)
      zb[pp][t] = (zb[pp][t] - meanl[pp]) * invl[pp] * g1 + b1;
    for (int w = t; w < PB * PHIH; w += 128) {
      int pp = w >> 6, u = w & 63;
      int j = jb + pp;
      float d0 = 0, d1 = 0, d2 = 0;
      if (j < cnt) { d0 = diffb[j][0]; d1 = diffb[j][1]; d2 = diffb[j][2]; }
      float hv = pb1[u] + d0 * pw1[u] + d1 * pw1[PHIH + u] + d2 * pw1[2 * PHIH + u];
      hbuf[pp][u] = gelu_f(hv);
    }
    __syncthreads();
    // 4. logits: thread (pp = t>>3, h = t&7): dot = zn . qW_h (+ TE)
    {
      int pp = t >> 3, h = t & 7;
      float dacc = 0;
      #pragma unroll
      for (int e4 = 0; e4 < 32; ++e4) {
        float4 zn4 = *(const float4*)&zb[pp][e4 * 4];
        float4 qw4 = *(const float4*)&qWg[h * EE + e4 * 4];
        dacc += zn4.x * qw4.x + zn4.y * qw4.y + zn4.z * qw4.z + zn4.w * qw4.w;
      }
      float te = pb2[h];
      #pragma unroll
      for (int u4 = 0; u4 < 16; ++u4) {
        float4 hb = *(const float4*)&hbuf[pp][u4 * 4];
        float4 p2 = *(const float4*)&pw2T[h][u4 * 4];
        te += hb.x * p2.x + hb.y * p2.y + hb.z * p2.z + hb.w * p2.w;
      }
      if (pp < nb) dotb[jb + pp][h] = dacc + te;
    }
    __syncthreads();
    // 5+6 fused: online softmax AND batch weights (8 threads; fast exp)
    if (t < HH) {
      float mold = mh[t], mb = mold;
      for (int pp = 0; pp < nb; ++pp) mb = fmaxf(mb, dotb[jb + pp][t]);
      float sc = __expf(mold - mb);
      float ls = lh[t] * sc;
      for (int pp = 0; pp < nb; ++pp) {
        float w = __expf(dotb[jb + pp][t] - mb);
        wsm[pp][t] = w;
        ls += w;
      }
      mh[t] = mb; lh[t] = ls; sch[t] = sc;
    }
    __syncthreads();
    // 7. zbar update (thread t = feature e), only valid rows
    {
      #pragma unroll
      for (int h = 0; h < 8; ++h) zbar[h] *= sch[h];
      for (int pp = 0; pp < nb; ++pp) {
        float znv = zb[pp][t];
        float4 wa = *(const float4*)&wsm[pp][0];
        float4 wb = *(const float4*)&wsm[pp][4];
        zbar[0] += wa.x * znv; zbar[1] += wa.y * znv; zbar[2] += wa.z * znv; zbar[3] += wa.w * znv;
        zbar[4] += wb.x * znv; zbar[5] += wb.y * znv; zbar[6] += wb.z * znv; zbar[7] += wb.w * znv;
      }
    }
    __syncthreads();
  }

  // epilogue: zbl aliases hbuf (8x128 floats fit in 16x68 = 1088)
  float* zbl = &hbuf[0][0];
  #pragma unroll
  for (int h = 0; h < 8; ++h) zbl[h * EE + t] = zbar[h];
  __syncthreads();
  int hh = t >> 4;
  float w0 = __expf(dot0g[hh] - mh[hh]) / lh[hh];
  float osum = 0.0f;
  for (int e4 = 0; e4 < 32; ++e4) {
    int e = e4 * 4;
    float4 zb4 = *(const float4*)&zbl[hh * EE + e];
    osum += zb4.x * Wv[(e + 0) * EE + t] + zb4.y * Wv[(e + 1) * EE + t]
          + zb4.z * Wv[(e + 2) * EE + t] + zb4.w * Wv[(e + 3) * EE + t];
  }
  osh[t] = w0 * v0g[t] + osum / lh[hh];
  if (t < cnt) {
    float s = 0;
    #pragma unroll
    for (int h2 = 0; h2 < HH; ++h2)
      s += __expf(dotb[t][h2] - mh[h2]) / lh[h2];
    asum[t] = s;
  }
  __syncthreads();
  float acc = 0;
  for (int e4 = 0; e4 < 32; ++e4) {
    int e = e4 * 4;
    float4 o4 = *(const float4*)&osh[e];
    acc += o4.x * Wo[(e + 0) * EE + t] + o4.y * Wo[(e + 1) * EE + t]
         + o4.z * Wo[(e + 2) * EE + t] + o4.w * Wo[(e + 3) * EE + t];
  }
  float zm = latent[t] + acc + bo[t];
  outz[(size_t)cell * EE + t] = zm;
  if (t < 3) {
    float a = 0;
    for (int j = 0; j < cnt; ++j) a += asum[j] * diffb[j][t];
    outx[(size_t)cell * 3 + t] = xqs[t] - a * (1.0f / 8.0f);
  }
}

// ---------------- D: FFN (8 rows per block, 512 threads, f32 in-place) ----------------
__global__ __launch_bounds__(512) void k_ffn(
    const float* __restrict__ ln2g, const float* __restrict__ ln2b,
    const float* __restrict__ fw1, const float* __restrict__ fb1,
    const float* __restrict__ fw2, const float* __restrict__ fb2,
    float* __restrict__ outz, int G) {
  __shared__ float zn[8][EE];
  __shared__ float zr[8][EE];
  __shared__ float gh[8][FFH];
  __shared__ float mv[8], sv[8];
  int t = threadIdx.x;
  int base = blockIdx.x * 8;
  for (int w = t; w < 8 * EE; w += 512) {
    int r = w >> 7, e = w & 127;
    int cell = base + r;
    float v = (cell < G) ? outz[(size_t)cell * EE + e] : 0.0f;
    zn[r][e] = v; zr[r][e] = v;
  }
  __syncthreads();
  {
    int r = t >> 6, lane = t & 63;
    float s = zn[r][lane] + zn[r][lane + 64];
    s += __shfl_xor(s, 1); s += __shfl_xor(s, 2); s += __shfl_xor(s, 4);
    s += __shfl_xor(s, 8); s += __shfl_xor(s, 16); s += __shfl_xor(s, 32);
    float mean = s * (1.0f / 128.0f);
    float d0 = zn[r][lane] - mean, d1 = zn[r][lane + 64] - mean;
    float v = d0 * d0 + d1 * d1;
    v += __shfl_xor(v, 1); v += __shfl_xor(v, 2); v += __shfl_xor(v, 4);
    v += __shfl_xor(v, 8); v += __shfl_xor(v, 16); v += __shfl_xor(v, 32);
    if (lane == 0) { mv[r] = mean; sv[r] = sqrtf(v * (1.0f / 128.0f) + 1e-5f); }
  }
  __syncthreads();
  for (int w = t; w < 8 * EE; w += 512) {
    int r = w >> 7, e = w & 127;
    zn[r][e] = (zn[r][e] - mv[r]) / sv[r] * ln2g[e] + ln2b[e];
  }
  __syncthreads();
  {
    int j = t;
    float acc[8];
    #pragma unroll
    for (int r = 0; r < 8; ++r) acc[r] = 0;
    for (int e = 0; e < EE; ++e) {
      float w = fw1[e * FFH + j];
      #pragma unroll
      for (int r = 0; r < 8; ++r) acc[r] += zn[r][e] * w;
    }
    float fb = fb1[j];
    #pragma unroll
    for (int r = 0; r < 8; ++r) gh[r][j] = gelu_f(acc[r] + fb);
  }
  __syncthreads();
  {
    int e = t & 127; int rb = (t >> 7) * 2;
    float a2[2];
    a2[0] = 0; a2[1] = 0;
    for (int j = 0; j < FFH; ++j) {
      float w = fw2[j * EE + e];
      a2[0] += gh[rb + 0][j] * w;
      a2[1] += gh[rb + 1][j] * w;
    }
    #pragma unroll
    for (int rr = 0; rr < 2; ++rr) {
      int cell = base + rb + rr;
      if (cell < G) outz[(size_t)cell * EE + e] = zr[rb + rr][e] + (a2[rr] + fb2[e]);
    }
  }
}

extern "C" void kernel_launch(void* const* d_in, const int* in_sizes, int n_in,
                              void* d_out, int out_size, void* d_ws, size_t ws_size,
                              hipStream_t stream) {
  const float* x     = (const float*)d_in[0];
  const float* z     = (const float*)d_in[1];
  const float* tgrid = (const float*)d_in[2];
  const float* latent= (const float*)d_in[3];
  const float* ln1g  = (const float*)d_in[4];
  const float* ln1b  = (const float*)d_in[5];
  const float* ln2g  = (const float*)d_in[6];
  const float* ln2b  = (const float*)d_in[7];
  const float* Wq    = (const float*)d_in[8];
  const float* Wk    = (const float*)d_in[9];
  const float* Wv    = (const float*)d_in[10];
  const float* Wo    = (const float*)d_in[11];
  const float* bo    = (const float*)d_in[12];
  const float* pw1   = (const float*)d_in[13];
  const float* pb1   = (const float*)d_in[14];
  const float* pw2   = (const float*)d_in[15];
  const float* pb2   = (const float*)d_in[16];
  const float* fw1   = (const float*)d_in[17];
  const float* fb1   = (const float*)d_in[18];
  const float* fw2   = (const float*)d_in[19];
  const float* fb2   = (const float*)d_in[20];
  (void)n_in; (void)ws_size;

  int Bn = in_sizes[2] / NTG;
  int BN = in_sizes[0] / 3;
  int N_ = BN / Bn;
  int G  = out_size / 131;
  int m  = G / Bn;

  char* ws = (char*)d_ws;
  unsigned* mm    = (unsigned*)ws;
  GridParams* gp  = (GridParams*)(ws + 64);
  float* qvec     = (float*)(ws + 128);
  float* v0g      = (float*)(ws + 128 + 512);
  float* dot0g    = (float*)(ws + 128 + 1024);
  float* qWg      = (float*)(ws + 2048);          // 8*128 f32 = 4096 B
  size_t off = 8192;
  int* counts     = (int*)(ws + off); off += (size_t)G * 4;
  int* offsets    = (int*)(ws + off); off += (size_t)G * 4;
  int* cursor     = (int*)(ws + off); off += (size_t)G * 4;
  int* compact    = (int*)(ws + off); off += (size_t)BN * 4;

  float* outx = (float*)d_out;
  float* outz = outx + (size_t)G * 3;

  hipLaunchKernelGGL(k_init, dim3((G + 255) / 256), dim3(256), 0, stream, mm, counts, cursor, G);
  hipLaunchKernelGGL(k_minmax, dim3(256), dim3(256), 0, stream, x, BN, mm);
  hipLaunchKernelGGL(k_bounds, dim3(1), dim3(64), 0, stream, mm, tgrid, gp);
  hipLaunchKernelGGL(k_precompute, dim3(1), dim3(128), 0, stream,
                     latent, ln1g, ln1b, Wq, Wk, Wv, pb1, pw2, pb2, qvec, v0g, dot0g, qWg);
  hipLaunchKernelGGL(k_assign, dim3((BN + 255) / 256), dim3(256), 0, stream,
                     x, gp, counts, BN, N_, m, G);
  hipLaunchKernelGGL(k_scan, dim3(1), dim3(1024), 0, stream, counts, offsets, G);
  hipLaunchKernelGGL(k_scatter, dim3((BN + 255) / 256), dim3(256), 0, stream,
                     x, gp, offsets, cursor, compact, BN, N_, m, G);
  hipLaunchKernelGGL(k_cell, dim3(G), dim3(128), 0, stream,
                     x, z, tgrid, latent, ln1g, ln1b, Wv, Wo, bo,
                     pw1, pb1, pw2, pb2, qWg, v0g, dot0g, gp, counts, offsets, compact,
                     outx, outz, m, BN);
  hipLaunchKernelGGL(k_ffn, dim3((G + 7) / 8), dim3(512), 0, stream,
                     ln2g, ln2b, fw1, fb1, fw2, fb2, outz, G);
}